// Round 17
// baseline (515.726 us; speedup 1.0000x reference)
//
#include <hip/hip_runtime.h>

typedef float f32x4 __attribute__((ext_vector_type(4)));

#define HH 128
#define WW 192
#define HO 256
#define WO 384
#define NINST 256
#define NPX (HH*WW)
#define OTY 16
#define LTY 10
#define LPAD 196
#define STRIPS 24
#define SY (127.0f/255.0f)
#define SX (191.0f/383.0f)
#define REP 8

// ================= PROBE V2: constant weights (cost = X + F) ===============
#define CW(i) (0.0011f * (float)(((i)*7) % 13) - 0.0031f)
__global__ __launch_bounds__(256) void probe_cw(
    const float* __restrict__ feats, const float* __restrict__ locs,
    const float* __restrict__ soi, const int* __restrict__ im_inds,
    const int* __restrict__ stride_p)
{
    const int n = blockIdx.y, t = threadIdx.x, oy0 = blockIdx.x * OTY;
    __shared__ float tile[LTY][LPAD];
    const int ly0 = (int)((float)oy0 * SY);
    const int   stride  = *stride_p;
    const float inv_soi = 1.0f / soi[n];
    const float loc_x = locs[2*n+0], loc_y = locs[2*n+1];
    const float* fbase = feats + im_inds[n] * (8*NPX);
    const float xstep  = -(float)stride * inv_soi;

    for (int it = 0; it < REP; ++it) {
        if (t < LTY * STRIPS) {
            const int r   = (unsigned)t / STRIPS;
            const int slo = t - r*STRIPS;
            const int c0  = (slo ^ (it & 7)) * 8;
            int gy = ly0 + r; if (gy > HH-1) gy = HH-1;
            const float* frow = fbase + gy*WW + c0;
            const float yrel = (loc_y - (float)(gy*stride + (stride>>1))) * inv_soi;
            const float xr0  = (loc_x - (float)(c0*stride + (stride>>1))) * inv_soi;

            #pragma unroll
            for (int g = 0; g < 2; ++g) {
                f32x4 f[8];
                #pragma unroll
                for (int ch = 0; ch < 8; ++ch)
                    f[ch] = *(const f32x4*)(frow + ch*NPX + g*4);
                float xr[4];
                #pragma unroll
                for (int j = 0; j < 4; ++j) xr[j] = fmaf((float)(g*4+j), xstep, xr0);
                float h0[4][8];
                #pragma unroll
                for (int o = 0; o < 8; ++o) {
                    const float byo = fmaf(yrel, CW(o*10+1), CW(152+o));
                    const float wxw = CW(o*10+0);
                    #pragma unroll
                    for (int j = 0; j < 4; ++j) {
                        float a = fmaf(xr[j], wxw, byo);
                        #pragma unroll
                        for (int ch = 0; ch < 8; ++ch)
                            a = fmaf(f[ch][j], CW(o*10+2+ch), a);
                        h0[j][o] = fmaxf(a, 0.0f);
                    }
                }
                f32x4 rv;
                #pragma unroll
                for (int j = 0; j < 4; ++j) rv[j] = CW(168);
                #pragma unroll
                for (int o = 0; o < 8; ++o) {
                    const float b1w = CW(160+o), w2w = CW(144+o);
                    #pragma unroll
                    for (int j = 0; j < 4; ++j) {
                        float a = b1w;
                        #pragma unroll
                        for (int c = 0; c < 8; ++c)
                            a = fmaf(h0[j][c], CW(80+o*8+c), a);
                        rv[j] = fmaf(fmaxf(a, 0.0f), w2w, rv[j]);
                    }
                }
                *(f32x4*)&tile[r][c0 + g*4] = rv;
            }
        }
        __syncthreads();
    }
    float acc = tile[t % LTY][(t * 13) % LPAD];
    asm volatile("" :: "v"(acc));
}

// ================= PROBE V3: synthetic features (cost = X + W) =============
__global__ __launch_bounds__(256) void probe_nf(
    const float* __restrict__ params, const float* __restrict__ locs,
    const float* __restrict__ soi, const int* __restrict__ stride_p)
{
    const int n = blockIdx.y, t = threadIdx.x, oy0 = blockIdx.x * OTY;
    __shared__ float tile[LTY][LPAD];
    const int ly0 = (int)((float)oy0 * SY);
    const float* __restrict__ pw = params + n * 169;
    const int   stride  = *stride_p;
    const float inv_soi = 1.0f / soi[n];
    const float loc_x = locs[2*n+0], loc_y = locs[2*n+1];
    const float xstep  = -(float)stride * inv_soi;

    for (int it = 0; it < REP; ++it) {
        if (t < LTY * STRIPS) {
            const int r   = (unsigned)t / STRIPS;
            const int slo = t - r*STRIPS;
            const int c0  = (slo ^ (it & 7)) * 8;
            int gy = ly0 + r; if (gy > HH-1) gy = HH-1;
            const float yrel = (loc_y - (float)(gy*stride + (stride>>1))) * inv_soi;
            const float xr0  = (loc_x - (float)(c0*stride + (stride>>1))) * inv_soi;
            const float fb = (float)((t ^ (it*37)) & 255) * 0.004f;

            #pragma unroll
            for (int g = 0; g < 2; ++g) {
                f32x4 f[8];
                #pragma unroll
                for (int ch = 0; ch < 8; ++ch) {
                    f[ch].x = fb + (float)(ch);   f[ch].y = fb + (float)(ch+1);
                    f[ch].z = fb + (float)(ch+2); f[ch].w = fb + (float)(ch+3);
                }
                float xr[4];
                #pragma unroll
                for (int j = 0; j < 4; ++j) xr[j] = fmaf((float)(g*4+j), xstep, xr0);
                float h0[4][8];
                #pragma unroll
                for (int o = 0; o < 8; ++o) {
                    const float byo = fmaf(yrel, pw[o*10+1], pw[152+o]);
                    const float wxw = pw[o*10+0];
                    #pragma unroll
                    for (int j = 0; j < 4; ++j) {
                        float a = fmaf(xr[j], wxw, byo);
                        #pragma unroll
                        for (int ch = 0; ch < 8; ++ch)
                            a = fmaf(f[ch][j], pw[o*10+2+ch], a);
                        h0[j][o] = fmaxf(a, 0.0f);
                    }
                }
                f32x4 rv;
                #pragma unroll
                for (int j = 0; j < 4; ++j) rv[j] = pw[168];
                #pragma unroll
                for (int o = 0; o < 8; ++o) {
                    const float b1w = pw[160+o], w2w = pw[144+o];
                    #pragma unroll
                    for (int j = 0; j < 4; ++j) {
                        float a = b1w;
                        #pragma unroll
                        for (int c = 0; c < 8; ++c)
                            a = fmaf(h0[j][c], pw[80+o*8+c], a);
                        rv[j] = fmaf(fmaxf(a, 0.0f), w2w, rv[j]);
                    }
                }
                *(f32x4*)&tile[r][c0 + g*4] = rv;
            }
        }
        __syncthreads();
    }
    float acc = tile[t % LTY][(t * 13) % LPAD];
    asm volatile("" :: "v"(acc));
}

// ================= REAL KERNEL (round-15 best, 50.0us) =====================
__global__ __launch_bounds__(256, 2) void dynmask_fused(
    const float* __restrict__ feats, const float* __restrict__ params,
    const float* __restrict__ locs, const float* __restrict__ soi,
    const int* __restrict__ im_inds, const int* __restrict__ stride_p,
    float* __restrict__ out)
{
    const int n = blockIdx.y, t = threadIdx.x, oy0 = blockIdx.x * OTY;
    __shared__ float tile[LTY][LPAD];
    const int ly0 = (int)((float)oy0 * SY);
    const float* __restrict__ pw = params + n * 169;
    const int   stride  = *stride_p;
    const float inv_soi = 1.0f / soi[n];
    const float loc_x = locs[2*n+0], loc_y = locs[2*n+1];
    const float* fbase = feats + im_inds[n] * (8*NPX);
    const float xstep  = -(float)stride * inv_soi;

    if (t < LTY * STRIPS) {
        const int r  = (unsigned)t / STRIPS;
        const int c0 = (t - r*STRIPS) * 8;
        int gy = ly0 + r; if (gy > HH-1) gy = HH-1;
        const float* frow = fbase + gy*WW + c0;
        const float yrel = (loc_y - (float)(gy*stride + (stride>>1))) * inv_soi;
        const float xr0  = (loc_x - (float)(c0*stride + (stride>>1))) * inv_soi;

        float w[169];
        #pragma unroll
        for (int i = 0; i < 169; ++i) w[i] = pw[i];

        float byo[8];
        #pragma unroll
        for (int o = 0; o < 8; ++o)
            byo[o] = fmaf(yrel, w[o*10+1], w[152+o]);

        #pragma unroll
        for (int g = 0; g < 2; ++g) {
            f32x4 f[8];
            #pragma unroll
            for (int ch = 0; ch < 8; ++ch)
                f[ch] = *(const f32x4*)(frow + ch*NPX + g*4);

            f32x4 rv;
            #pragma unroll
            for (int j = 0; j < 4; ++j) {
                const float xrj = fmaf((float)(g*4+j), xstep, xr0);
                float h0[8];
                #pragma unroll
                for (int o = 0; o < 8; ++o) {
                    float a = fmaf(xrj, w[o*10+0], byo[o]);
                    #pragma unroll
                    for (int ch = 0; ch < 8; ++ch)
                        a = fmaf(f[ch][j], w[o*10+2+ch], a);
                    h0[o] = fmaxf(a, 0.0f);
                }
                float acc = w[168];
                #pragma unroll
                for (int o = 0; o < 8; ++o) {
                    float a = w[160+o];
                    #pragma unroll
                    for (int c = 0; c < 8; ++c)
                        a = fmaf(h0[c], w[80+o*8+c], a);
                    acc = fmaf(fmaxf(a, 0.0f), w[144+o], acc);
                }
                rv[j] = acc;
            }
            *(f32x4*)&tile[r][c0 + g*4] = rv;
        }
    }

    __syncthreads();

    float* obase = out + (size_t)n * (HO*WO);
    #pragma unroll
    for (int k = 0; k < 3; ++k) {
        const int u    = t + k*256;
        const int wrap = (u >= 384);
        const int col  = wrap ? u - 384 : u;
        const int r0o  = wrap ? 8 : 0;
        const int v0   = oy0 + r0o;

        const float xsf = (float)col * SX;
        int ix0 = (int)xsf; if (ix0 > WW-2) ix0 = WW-2;
        const float wx = xsf - (float)ix0;

        const float ysf0 = (float)v0 * SY;
        const int   iyA  = (int)ysf0;
        const int   base = iyA - ly0;
        const float f0   = ysf0 - (float)iyA;

        const float* tc = &tile[base][ix0];
        float pa0 = tc[0],        pb0 = tc[1];
        float pa1 = tc[1*LPAD],   pb1 = tc[1*LPAD+1];
        float pa2 = tc[2*LPAD],   pb2 = tc[2*LPAD+1];
        float pa3 = tc[3*LPAD],   pb3 = tc[3*LPAD+1];
        float pa4 = tc[4*LPAD],   pb4 = tc[4*LPAD+1];
        float pa5 = tc[5*LPAD],   pb5 = tc[5*LPAD+1];

        float* optr = obase + (size_t)v0 * WO + col;

        #define EMIT_ROW(RR, MLO)                                            \
        {                                                                    \
            const float wy = fmaf((float)(RR), SY, f0) - (float)(MLO);       \
            const float va = fmaf(wy, pa##MLO##N - pa##MLO, pa##MLO);        \
            const float vb = fmaf(wy, pb##MLO##N - pb##MLO, pb##MLO);        \
            *optr = fmaf(wx, vb - va, va);                                   \
            optr += WO;                                                      \
        }
        #define pa0N pa1
        #define pa1N pa2
        #define pa2N pa3
        #define pa3N pa4
        #define pa4N pa5
        #define pb0N pb1
        #define pb1N pb2
        #define pb2N pb3
        #define pb3N pb4
        #define pb4N pb5

        if (v0 == 0) {
            EMIT_ROW(0,0) EMIT_ROW(1,0) EMIT_ROW(2,0) EMIT_ROW(3,1)
            EMIT_ROW(4,1) EMIT_ROW(5,2) EMIT_ROW(6,2) EMIT_ROW(7,3)
        } else {
            EMIT_ROW(0,0) EMIT_ROW(1,1) EMIT_ROW(2,1) EMIT_ROW(3,2)
            EMIT_ROW(4,2) EMIT_ROW(5,3) EMIT_ROW(6,3) EMIT_ROW(7,4)
        }
        #undef EMIT_ROW
        #undef pa0N
        #undef pa1N
        #undef pa2N
        #undef pa3N
        #undef pa4N
        #undef pb0N
        #undef pb1N
        #undef pb2N
        #undef pb3N
        #undef pb4N
    }
}

extern "C" void kernel_launch(void* const* d_in, const int* in_sizes, int n_in,
                              void* d_out, int out_size, void* d_ws, size_t ws_size,
                              hipStream_t stream) {
    const float* feats    = (const float*)d_in[0];
    const float* params   = (const float*)d_in[1];
    const float* locs     = (const float*)d_in[2];
    const float* soi      = (const float*)d_in[3];
    const int*   im_inds  = (const int*)d_in[4];
    const int*   stride_p = (const int*)d_in[6];
    float* out = (float*)d_out;

    dim3 grid(HO / OTY, NINST);
    dim3 block(256);

    // --- the two ablation probes, individually visible this time ---
    hipLaunchKernelGGL(probe_cw, grid, block, 0, stream,
                       feats, locs, soi, im_inds, stride_p);
    hipLaunchKernelGGL(probe_nf, grid, block, 0, stream,
                       params, locs, soi, stride_p);

    // --- real kernel last: fully overwrites d_out ---
    hipLaunchKernelGGL(dynmask_fused, grid, block, 0, stream,
                       feats, params, locs, soi, im_inds, stride_p, out);
}

// Round 18
// 45.338 us; speedup vs baseline: 11.3752x; 11.3752x over previous
//
#include <hip/hip_runtime.h>

typedef float f32x4 __attribute__((ext_vector_type(4)));

#define HH 128
#define WW 192
#define HO 256
#define WO 384
#define NINST 256
#define NPX (HH*WW)
#define OTY 16
#define LTY 10
#define LPAD 196
#define STRIPS 24
#define SY (127.0f/255.0f)
#define SX (191.0f/383.0f)

// Weights forced onto the VECTOR path: params -> LDS once per block, then 43x
// ds_read_b128 into per-thread VGPRs (compile-time indices). r17 probes:
// MLP 40us = 13 FMA + 18 weight-path (scalar-L1 refill serialization; SGPR
// file can't hold 169) + 7 feature-path. ds_read results live in VGPRs --
// no SGPR cap, no scalar-port contention, broadcast conflict-free.
__global__ __launch_bounds__(256, 2) void dynmask_fused(
    const float* __restrict__ feats,    // (2, 8, 128, 192) NCHW
    const float* __restrict__ params,   // (256, 169)
    const float* __restrict__ locs,     // (256, 2) [x, y]
    const float* __restrict__ soi,      // (256,)
    const int*   __restrict__ im_inds,  // (256,)
    const int*   __restrict__ stride_p, // (1,)
    float* __restrict__ out)            // (256, 1, 256, 384)
{
    const int n   = blockIdx.y;
    const int t   = threadIdx.x;
    const int oy0 = blockIdx.x * OTY;

    __shared__ float tile[LTY][LPAD];   // 7840 B
    __shared__ float wlds[172];         // 169 weights, padded to 43*4

    const int ly0 = (int)((float)oy0 * SY);

    // wave-uniform scalars
    const int   stride  = *stride_p;
    const float inv_soi = 1.0f / soi[n];
    const float loc_x   = locs[2*n+0];
    const float loc_y   = locs[2*n+1];
    const float* fbase  = feats + im_inds[n] * (8*NPX);
    const float xstep   = -(float)stride * inv_soi;

    // ---- stage params into LDS (vector path from here on) ----
    if (t < 172) wlds[t] = (t < 169) ? params[n*169 + t] : 0.0f;
    __syncthreads();

    // ---- MLP: 240 threads, one 8-px strip each ----
    if (t < LTY * STRIPS) {
        const int r  = (unsigned)t / STRIPS;          // 0..9
        const int c0 = (t - r*STRIPS) * 8;
        int gy = ly0 + r; if (gy > HH-1) gy = HH-1;
        const float* frow = fbase + gy*WW + c0;

        const float yrel = (loc_y - (float)(gy*stride + (stride>>1))) * inv_soi;
        const float xr0  = (loc_x - (float)(c0*stride + (stride>>1))) * inv_soi;

        // ---- bulk LDS -> VGPR weight load: 43 x ds_read_b128 ----
        f32x4 wq[43];
        #pragma unroll
        for (int i = 0; i < 43; ++i)
            wq[i] = *(const f32x4*)&wlds[i*4];
        #define W(i) (wq[(i)>>2][(i)&3])

        float byo[8];
        #pragma unroll
        for (int o = 0; o < 8; ++o)
            byo[o] = fmaf(yrel, W(o*10+1), W(152+o));   // y-term hoisted

        #pragma unroll
        for (int g = 0; g < 2; ++g) {
            f32x4 f[8];
            #pragma unroll
            for (int ch = 0; ch < 8; ++ch)
                f[ch] = *(const f32x4*)(frow + ch*NPX + g*4);

            f32x4 rv;
            #pragma unroll
            for (int j = 0; j < 4; ++j) {
                const float xrj = fmaf((float)(g*4+j), xstep, xr0);

                float h0[8];
                #pragma unroll
                for (int o = 0; o < 8; ++o) {
                    float a = fmaf(xrj, W(o*10+0), byo[o]);
                    #pragma unroll
                    for (int ch = 0; ch < 8; ++ch)
                        a = fmaf(f[ch][j], W(o*10+2+ch), a);
                    h0[o] = fmaxf(a, 0.0f);
                }

                float acc = W(168);
                #pragma unroll
                for (int o = 0; o < 8; ++o) {
                    float a = W(160+o);
                    #pragma unroll
                    for (int c = 0; c < 8; ++c)
                        a = fmaf(h0[c], W(80+o*8+c), a);
                    acc = fmaf(fmaxf(a, 0.0f), W(144+o), acc);
                }
                rv[j] = acc;
            }
            *(f32x4*)&tile[r][c0 + g*4] = rv;
        }
        #undef W
    }

    __syncthreads();

    // ---- upsample: 3 units/thread, unit = (one column, 8 rows) ----
    float* obase = out + (size_t)n * (HO*WO);
    #pragma unroll
    for (int k = 0; k < 3; ++k) {
        const int u    = t + k*256;          // 0..767
        const int wrap = (u >= 384);         // wave-uniform
        const int col  = wrap ? u - 384 : u; // 0..383
        const int r0o  = wrap ? 8 : 0;
        const int v0   = oy0 + r0o;

        const float xsf = (float)col * SX;
        int ix0 = (int)xsf; if (ix0 > WW-2) ix0 = WW-2;
        const float wx = xsf - (float)ix0;

        const float ysf0 = (float)v0 * SY;
        const int   iyA  = (int)ysf0;        // <=123, no clamp needed
        const int   base = iyA - ly0;        // 0..4
        const float f0   = ysf0 - (float)iyA;

        // 6 independent ds_read2_b32 pairs issued upfront
        const float* tc = &tile[base][ix0];
        float pa0 = tc[0],        pb0 = tc[1];
        float pa1 = tc[1*LPAD],   pb1 = tc[1*LPAD+1];
        float pa2 = tc[2*LPAD],   pb2 = tc[2*LPAD+1];
        float pa3 = tc[3*LPAD],   pb3 = tc[3*LPAD+1];
        float pa4 = tc[4*LPAD],   pb4 = tc[4*LPAD+1];
        float pa5 = tc[5*LPAD],   pb5 = tc[5*LPAD+1];

        float* optr = obase + (size_t)v0 * WO + col;

        #define EMIT_ROW(RR, MLO)                                            \
        {                                                                    \
            const float wy = fmaf((float)(RR), SY, f0) - (float)(MLO);       \
            const float va = fmaf(wy, pa##MLO##N - pa##MLO, pa##MLO);        \
            const float vb = fmaf(wy, pb##MLO##N - pb##MLO, pb##MLO);        \
            *optr = fmaf(wx, vb - va, va);                                   \
            optr += WO;                                                      \
        }
        #define pa0N pa1
        #define pa1N pa2
        #define pa2N pa3
        #define pa3N pa4
        #define pa4N pa5
        #define pb0N pb1
        #define pb1N pb2
        #define pb2N pb3
        #define pb3N pb4
        #define pb4N pb5

        if (v0 == 0) {
            // pattern A: m = 0,0,0,1,1,2,2,3  (only oy0=0, r0o=0)
            EMIT_ROW(0,0) EMIT_ROW(1,0) EMIT_ROW(2,0) EMIT_ROW(3,1)
            EMIT_ROW(4,1) EMIT_ROW(5,2) EMIT_ROW(6,2) EMIT_ROW(7,3)
        } else {
            // pattern B: m = 0,1,1,2,2,3,3,4  (all other half-bands)
            EMIT_ROW(0,0) EMIT_ROW(1,1) EMIT_ROW(2,1) EMIT_ROW(3,2)
            EMIT_ROW(4,2) EMIT_ROW(5,3) EMIT_ROW(6,3) EMIT_ROW(7,4)
        }
        #undef EMIT_ROW
        #undef pa0N
        #undef pa1N
        #undef pa2N
        #undef pa3N
        #undef pa4N
        #undef pb0N
        #undef pb1N
        #undef pb2N
        #undef pb3N
        #undef pb4N
    }
}

extern "C" void kernel_launch(void* const* d_in, const int* in_sizes, int n_in,
                              void* d_out, int out_size, void* d_ws, size_t ws_size,
                              hipStream_t stream) {
    const float* feats    = (const float*)d_in[0];
    const float* params   = (const float*)d_in[1];
    const float* locs     = (const float*)d_in[2];
    const float* soi      = (const float*)d_in[3];
    const int*   im_inds  = (const int*)d_in[4];
    // d_in[5] = fpn_levels (folded into sizes_of_interest)
    const int*   stride_p = (const int*)d_in[6];
    float* out = (float*)d_out;

    dim3 grid(HO / OTY, NINST);   // (16, 256) = 4096 blocks
    dim3 block(256);
    hipLaunchKernelGGL(dynmask_fused, grid, block, 0, stream,
                       feats, params, locs, soi, im_inds, stride_p, out);
}